// Round 3
// baseline (356.188 us; speedup 1.0000x reference)
//
#include <hip/hip_runtime.h>
#include <hip/hip_bf16.h>

#define RMAXF 2.0f
#define PI_F 3.14159265358979f

// Per-4-edge processing:
//   dr_vec is (N,3) f32  -> 3 x float4 per quad of edges (48 B, 16B-aligned)
//   idx    is (2, N) i32 -> int4 gathers of idx_i / idx_j per quad
// Tables |rep_prefactor|, |rep_scale| staged in LDS as float2[119].
// Grid-stride, wave64 shuffle reduce, one atomicAdd per block.

__global__ __launch_bounds__(256) void edge_kernel(
    const float4* __restrict__ dr4,
    const int*    __restrict__ idx_i,
    const int*    __restrict__ idx_j,
    const int*    __restrict__ Z,
    const float*  __restrict__ rep_scale,
    const float*  __restrict__ rep_prefactor,
    float*        __restrict__ out,
    int n_quads, int n_edges)
{
    __shared__ float2 tab[128];   // (A=|prefactor|, R=|scale|)
    for (int t = threadIdx.x; t < 119; t += blockDim.x)
        tab[t] = make_float2(fabsf(rep_prefactor[t]), fabsf(rep_scale[t]));
    __syncthreads();

    float acc = 0.0f;
    const int stride = gridDim.x * blockDim.x;

    for (int q = blockIdx.x * blockDim.x + threadIdx.x; q < n_quads; q += stride) {
        // 4 edges worth of dr_vec: 12 floats
        float4 a = dr4[3 * q + 0];
        float4 b = dr4[3 * q + 1];
        float4 c = dr4[3 * q + 2];
        int4 i4 = ((const int4*)idx_i)[q];
        int4 j4 = ((const int4*)idx_j)[q];

        float d2[4];
        d2[0] = a.x * a.x + a.y * a.y + a.z * a.z;
        d2[1] = a.w * a.w + b.x * b.x + b.y * b.y;
        d2[2] = b.z * b.z + b.w * b.w + c.x * c.x;
        d2[3] = c.y * c.y + c.z * c.z + c.w * c.w;

        int ii[4] = { i4.x, i4.y, i4.z, i4.w };
        int jj[4] = { j4.x, j4.y, j4.z, j4.w };

        // hoist the 8 divergent gathers so they overlap
        int zi[4], zj[4];
        #pragma unroll
        for (int k = 0; k < 4; ++k) { zi[k] = Z[ii[k]]; zj[k] = Z[jj[k]]; }

        #pragma unroll
        for (int k = 0; k < 4; ++k) {
            float dr = __builtin_amdgcn_sqrtf(d2[k]);
            dr = fminf(fmaxf(dr, 0.02f), RMAXF);
            float cc = 0.5f * (__cosf((PI_F / RMAXF) * dr) + 1.0f);
            float2 pi_ = tab[zi[k]];
            float2 pj_ = tab[zj[k]];
            float inv_rr = __builtin_amdgcn_rcpf(pi_.y * pj_.y);
            float e  = __expf(-dr * (pi_.y + pj_.y) * inv_rr);
            float f  = pi_.x * pj_.x * e * __builtin_amdgcn_rcpf(dr * dr);
            f *= cc;
            acc += (ii[k] != jj[k]) ? f : 0.0f;
        }
    }

    // tail edges (n_edges % 4), handled by one thread — n_edges is 12.8M so
    // this is normally empty, kept for generality
    if (blockIdx.x == 0 && threadIdx.x == 0) {
        const float* drf = (const float*)dr4;
        for (int e = n_quads * 4; e < n_edges; ++e) {
            float x = drf[3 * e + 0], y = drf[3 * e + 1], z = drf[3 * e + 2];
            float dr = sqrtf(x * x + y * y + z * z);
            dr = fminf(fmaxf(dr, 0.02f), RMAXF);
            float cc = 0.5f * (__cosf((PI_F / RMAXF) * dr) + 1.0f);
            int i = idx_i[e], j = idx_j[e];
            float2 pi_ = tab[Z[i]];
            float2 pj_ = tab[Z[j]];
            float e_ = __expf(-dr * (pi_.y + pj_.y) / (pi_.y * pj_.y));
            float f  = pi_.x * pj_.x * e_ / (dr * dr) * cc;
            if (i != j) acc += f;
        }
    }

    // wave64 reduction
    #pragma unroll
    for (int off = 32; off > 0; off >>= 1)
        acc += __shfl_down(acc, off, 64);

    __shared__ float wsum[4];
    int lane = threadIdx.x & 63;
    int wid  = threadIdx.x >> 6;
    if (lane == 0) wsum[wid] = acc;
    __syncthreads();
    if (threadIdx.x == 0) {
        float s = wsum[0] + wsum[1] + wsum[2] + wsum[3];
        atomicAdd(out, s);
    }
}

extern "C" void kernel_launch(void* const* d_in, const int* in_sizes, int n_in,
                              void* d_out, int out_size, void* d_ws, size_t ws_size,
                              hipStream_t stream) {
    // inputs: 0=R, 1=dr_vec, 2=Z, 3=idx, 4=box, 5=properties, 6=rep_scale, 7=rep_prefactor
    const float* dr_vec        = (const float*)d_in[1];
    const int*   Z             = (const int*)d_in[2];
    const int*   idx           = (const int*)d_in[3];
    const float* rep_scale     = (const float*)d_in[6];
    const float* rep_prefactor = (const float*)d_in[7];
    float* out = (float*)d_out;

    const int n_edges = in_sizes[3] / 2;     // idx is (2, N_EDGES)
    const int n_quads = n_edges / 4;
    const int* idx_i = idx;
    const int* idx_j = idx + n_edges;

    // d_out is poisoned 0xAA before every replay — zero it on-stream
    hipMemsetAsync(d_out, 0, sizeof(float), stream);

    int blocks = (n_quads + 255) / 256;
    if (blocks > 2048) blocks = 2048;
    edge_kernel<<<blocks, 256, 0, stream>>>(
        (const float4*)dr_vec, idx_i, idx_j, Z, rep_scale, rep_prefactor,
        out, n_quads, n_edges);
}